// Round 2
// baseline (401.080 us; speedup 1.0000x reference)
//
#include <hip/hip_runtime.h>
#include <hip/hip_bf16.h>

#define B  32
#define T  8192
#define H  256
#define NC 32      // T-chunks per batch
#define CT 256     // rows per chunk (NC*CT == T)

// ---------------------------------------------------------------------------
// Kernel 1: v[b,h] = sum_o W1[o,h] * h_t[b,o],   h_t[b] = hs[b, T-1, :]
// score[b,t] = hs[b,t,:] . v[b]  algebraically replaces the (B,T,H) einsum.
// ---------------------------------------------------------------------------
__global__ void k_v(const float* __restrict__ hs,
                    const float* __restrict__ W1,
                    float* __restrict__ v) {
    int b = blockIdx.x, tid = threadIdx.x;  // 256 threads
    __shared__ float ht[H];
    ht[tid] = hs[((size_t)(b * T + (T - 1))) * H + tid];
    __syncthreads();
    float acc = 0.f;
    for (int o = 0; o < H; ++o)
        acc += W1[o * H + tid] * ht[o];     // coalesced over tid
    v[b * H + tid] = acc;
}

// ---------------------------------------------------------------------------
// Kernel 2 (fused, single pass over hs): per (b, chunk) block of 256 rows:
//   score[b,t] (raw, to ws) + online-softmax partials (m,l) + partial context.
// 4 waves/block, each wave owns 64 rows; lane owns 4 h-columns (float4).
// ---------------------------------------------------------------------------
__global__ void k_fused(const float* __restrict__ hs,
                        const float* __restrict__ v,
                        float* __restrict__ score,
                        float* __restrict__ mpart,
                        float* __restrict__ lpart,
                        float* __restrict__ ctxp) {
    int b = blockIdx.x, tc = blockIdx.y;
    int tid = threadIdx.x, wave = tid >> 6, lane = tid & 63;
    __shared__ float vs[H];
    __shared__ float wm[4], wl[4];
    __shared__ float wctx[4 * H];
    vs[tid] = v[b * H + tid];
    __syncthreads();
    float v0 = vs[lane * 4 + 0], v1 = vs[lane * 4 + 1];
    float v2 = vs[lane * 4 + 2], v3 = vs[lane * 4 + 3];

    const float* base = hs + ((size_t)(b * T + tc * CT)) * H;
    float m = -1e30f, l = 0.f;
    float c0 = 0.f, c1 = 0.f, c2 = 0.f, c3 = 0.f;

    for (int i = 0; i < 64; ++i) {
        int row = wave * 64 + i;
        float4 u = *(const float4*)(base + (size_t)row * H + lane * 4);
        float s = u.x * v0 + u.y * v1 + u.z * v2 + u.w * v3;
        #pragma unroll
        for (int mk = 1; mk < 64; mk <<= 1)
            s += __shfl_xor(s, mk, 64);      // all lanes end with full dot
        if (lane == 0)
            score[b * T + tc * CT + row] = s;
        float mn    = fmaxf(m, s);
        float alpha = expf(m - mn);          // first iter: expf(-1e30-s) = 0
        float p     = expf(s - mn);
        l  = l  * alpha + p;
        c0 = c0 * alpha + p * u.x;
        c1 = c1 * alpha + p * u.y;
        c2 = c2 * alpha + p * u.z;
        c3 = c3 * alpha + p * u.w;
        m  = mn;
    }

    // combine 4 waves within the block
    if (lane == 0) { wm[wave] = m; wl[wave] = l; }
    wctx[wave * H + lane * 4 + 0] = c0;
    wctx[wave * H + lane * 4 + 1] = c1;
    wctx[wave * H + lane * 4 + 2] = c2;
    wctx[wave * H + lane * 4 + 3] = c3;
    __syncthreads();

    float bm = fmaxf(fmaxf(wm[0], wm[1]), fmaxf(wm[2], wm[3]));
    float e0 = expf(wm[0] - bm), e1 = expf(wm[1] - bm);
    float e2 = expf(wm[2] - bm), e3 = expf(wm[3] - bm);
    float cc = wctx[0 * H + tid] * e0 + wctx[1 * H + tid] * e1
             + wctx[2 * H + tid] * e2 + wctx[3 * H + tid] * e3;
    ctxp[((size_t)(b * NC + tc)) * H + tid] = cc;
    if (tid == 0) {
        mpart[b * NC + tc] = bm;
        lpart[b * NC + tc] = wl[0] * e0 + wl[1] * e1 + wl[2] * e2 + wl[3] * e3;
    }
}

// ---------------------------------------------------------------------------
// Kernel 3: combine chunk partials -> ctx[b,:]; pre = [ctx, h_t];
//           out_av[b,o] = tanh( pre . W2[o,:] ).  Also writes (M,L) stats.
// ---------------------------------------------------------------------------
__global__ void k_final(const float* __restrict__ hs,
                        const float* __restrict__ W2,
                        const float* __restrict__ ctxp,
                        const float* __restrict__ mpart,
                        const float* __restrict__ lpart,
                        float* __restrict__ stats,
                        float* __restrict__ out_av) {
    int b = blockIdx.x, tid = threadIdx.x;  // 256 threads
    __shared__ float pre[2 * H];
    float M = -1e30f;
    for (int c = 0; c < NC; ++c) M = fmaxf(M, mpart[b * NC + c]);
    float L = 0.f, cc = 0.f;
    for (int c = 0; c < NC; ++c) {
        float e = expf(mpart[b * NC + c] - M);
        L  += lpart[b * NC + c] * e;
        cc += ctxp[((size_t)(b * NC + c)) * H + tid] * e;
    }
    pre[tid]     = cc / L;
    pre[H + tid] = hs[((size_t)(b * T + (T - 1))) * H + tid];
    if (tid == 0) { stats[b * 2] = M; stats[b * 2 + 1] = L; }
    __syncthreads();
    const float4* w2r = (const float4*)(W2 + (size_t)tid * (2 * H));
    float acc = 0.f;
    #pragma unroll 4
    for (int j = 0; j < (2 * H) / 4; ++j) {
        float4 u = w2r[j];
        acc += pre[4 * j + 0] * u.x + pre[4 * j + 1] * u.y
             + pre[4 * j + 2] * u.z + pre[4 * j + 3] * u.w;
    }
    out_av[b * H + tid] = tanhf(acc);
}

// ---------------------------------------------------------------------------
// Kernel 4: attention_weights[b,t] = exp(score[b,t] - M[b]) / L[b]
// ---------------------------------------------------------------------------
__global__ void k_weights(const float* __restrict__ score,
                          const float* __restrict__ stats,
                          float* __restrict__ out_aw) {
    int b = blockIdx.x;
    int t = blockIdx.y * 1024 + threadIdx.x;
    float M = stats[b * 2], L = stats[b * 2 + 1];
    out_aw[b * T + t] = expf(score[b * T + t] - M) / L;
}

extern "C" void kernel_launch(void* const* d_in, const int* in_sizes, int n_in,
                              void* d_out, int out_size, void* d_ws, size_t ws_size,
                              hipStream_t stream) {
    const float* hs = (const float*)d_in[0];
    const float* W1 = (const float*)d_in[1];
    const float* W2 = (const float*)d_in[2];
    float* out    = (float*)d_out;
    float* out_av = out;              // attention_vector  [B*H  = 8192]
    float* out_aw = out + B * H;      // attention_weights [B*T  = 262144]

    float* ws    = (float*)d_ws;
    float* v     = ws;                              // 8192
    float* score = v + B * H;                       // 262144
    float* mpart = score + B * T;                   // 1024
    float* lpart = mpart + B * NC;                  // 1024
    float* ctxp  = lpart + B * NC;                  // 262144
    float* stats = ctxp + (size_t)B * NC * H;       // 64
    // total ws: ~2.1 MB

    k_v      <<<dim3(B),       256,  0, stream>>>(hs, W1, v);
    k_fused  <<<dim3(B, NC),   256,  0, stream>>>(hs, v, score, mpart, lpart, ctxp);
    k_final  <<<dim3(B),       256,  0, stream>>>(hs, W2, ctxp, mpart, lpart, stats, out_av);
    k_weights<<<dim3(B, 8),    1024, 0, stream>>>(score, stats, out_aw);
}